// Round 5
// baseline (423.422 us; speedup 1.0000x reference)
//
#include <hip/hip_runtime.h>
#include <hip/hip_fp16.h>
#include <math.h>

#define N_NODES 50000
#define E_EDGES 800000
#define NEG_SLOPE 0.2f
#define BN_EPS 1e-5f
#define SCAN_NBLK ((N_NODES + 1023) / 1024)  // 49
#define NB 25          // coarse buckets: dst >> 11 (2048 nodes each)
#define BIN_K 384      // LDS entries per bin
#define BIN_FLUSH 128  // flush threshold (invariant: fill<128 at tile start, +256 max <= 384)
#define BIN_NBLK 256
#define BIN_CHUNK ((E_EDGES + BIN_NBLK - 1) / BIN_NBLK)  // 3125

__device__ __forceinline__ float lrelu(float v) { return v > 0.f ? v : NEG_SLOPE * v; }

// ---------------- init ----------------
__global__ void k_zero(int* __restrict__ counts, float* __restrict__ bn_sum,
                       float* __restrict__ bn_sumsq) {
  int i = blockIdx.x * 256 + threadIdx.x;
  if (i < N_NODES + 1) counts[i] = 0;
  if (i < 128) { bn_sum[i] = 0.f; bn_sumsq[i] = 0.f; }
}

// ---------------- CSR build ----------------
__global__ void k_hist(const int* __restrict__ dst, int* __restrict__ counts) {
  int e = blockIdx.x * 256 + threadIdx.x;
  if (e < E_EDGES) atomicAdd(&counts[dst[e]], 1);
}

// hierarchical exclusive scan: 49 blocks x 256 threads x 4 elements
__global__ __launch_bounds__(256) void k_scan1(const int* __restrict__ counts,
                                               int* __restrict__ tmp_scan,
                                               int* __restrict__ blk_sums) {
  __shared__ int ts[256];
  int t = threadIdx.x;
  int base = blockIdx.x * 1024 + t * 4;
  int c0 = (base + 0 < N_NODES) ? counts[base + 0] : 0;
  int c1 = (base + 1 < N_NODES) ? counts[base + 1] : 0;
  int c2 = (base + 2 < N_NODES) ? counts[base + 2] : 0;
  int c3 = (base + 3 < N_NODES) ? counts[base + 3] : 0;
  int s = c0 + c1 + c2 + c3;
  ts[t] = s;
  __syncthreads();
  for (int off = 1; off < 256; off <<= 1) {
    int v = (t >= off) ? ts[t - off] : 0;
    __syncthreads();
    ts[t] += v;
    __syncthreads();
  }
  int excl = ts[t] - s;
  if (t == 255) blk_sums[blockIdx.x] = ts[255];
  if (base + 0 < N_NODES) tmp_scan[base + 0] = excl;
  if (base + 1 < N_NODES) tmp_scan[base + 1] = excl + c0;
  if (base + 2 < N_NODES) tmp_scan[base + 2] = excl + c0 + c1;
  if (base + 3 < N_NODES) tmp_scan[base + 3] = excl + c0 + c1 + c2;
}

__global__ void k_scan2(int* __restrict__ blk_sums) {
  int t = threadIdx.x;  // single 64-lane wave
  int orig = (t < SCAN_NBLK) ? blk_sums[t] : 0;
  int v = orig;
#pragma unroll
  for (int off = 1; off < 64; off <<= 1) {
    int u = __shfl_up(v, off);
    if (t >= off) v += u;
  }
  if (t < SCAN_NBLK) blk_sums[t] = v - orig;  // exclusive
}

__global__ __launch_bounds__(256) void k_scan3(const int* __restrict__ tmp_scan,
                                               const int* __restrict__ blk_sums,
                                               int* __restrict__ row_ptr,
                                               int* __restrict__ cursor,
                                               int* __restrict__ bin_cursor) {
  int i = blockIdx.x * 256 + threadIdx.x;
  if (i < N_NODES) {
    int v = tmp_scan[i] + blk_sums[i >> 10];
    row_ptr[i] = v;
    cursor[i] = v;
    if ((i & 2047) == 0) bin_cursor[i >> 11] = v;  // coarse-bucket write cursors
  }
  if (i == 0) row_ptr[N_NODES] = E_EDGES;  // counts always sum to E
}

// ---- pass 1: LDS multisplit into 25 coarse buckets; packed (src<<16)|dst (both < 2^16) ----
__global__ __launch_bounds__(256) void k_bin(const int* __restrict__ src,
                                             const int* __restrict__ dst,
                                             int* __restrict__ bin_cursor,
                                             unsigned int* __restrict__ binned) {
  __shared__ unsigned int bins[NB][BIN_K];  // 25*384*4 = 38.4 KB
  __shared__ int fill[NB];
  __shared__ int flush_base[NB];
  int t = threadIdx.x;
  if (t < NB) fill[t] = 0;
  __syncthreads();
  int chunkBeg = blockIdx.x * BIN_CHUNK;
  int chunkEnd = chunkBeg + BIN_CHUNK;
  if (chunkEnd > E_EDGES) chunkEnd = E_EDGES;
  for (int base = chunkBeg; base < chunkEnd; base += 256) {
    int e = base + t;
    if (e < chunkEnd) {
      unsigned int d = (unsigned int)dst[e];
      int b = d >> 11;
      int pos = atomicAdd(&fill[b], 1);
      bins[b][pos] = ((unsigned int)src[e] << 16) | d;
    }
    __syncthreads();
    if (t < NB) {
      int f = fill[t];
      flush_base[t] = (f >= BIN_FLUSH) ? atomicAdd(&bin_cursor[t], f) : -1;
    }
    __syncthreads();
    for (int b = 0; b < NB; b++) {
      int fb = flush_base[b];
      if (fb >= 0) {
        int f = fill[b];
        for (int k = t; k < f; k += 256) binned[fb + k] = bins[b][k];
      }
    }
    __syncthreads();
    if (t < NB && flush_base[t] >= 0) fill[t] = 0;
    __syncthreads();
  }
  // final flush
  if (t < NB) {
    int f = fill[t];
    flush_base[t] = (f > 0) ? atomicAdd(&bin_cursor[t], f) : -1;
  }
  __syncthreads();
  for (int b = 0; b < NB; b++) {
    int fb = flush_base[b];
    if (fb >= 0) {
      int f = fill[b];
      for (int k = t; k < f; k += 256) binned[fb + k] = bins[b][k];
    }
  }
}

// ---- pass 2: one block per bucket -> all csr_src writes to a window come from one XCD ----
__global__ __launch_bounds__(1024) void k_scatter2(const int* __restrict__ row_ptr,
                                                   const unsigned int* __restrict__ binned,
                                                   int* __restrict__ cursor,
                                                   int* __restrict__ csr_src) {
  int b = blockIdx.x;
  int beg = row_ptr[b << 11];
  int hi = (b + 1) << 11;
  int end = row_ptr[hi < N_NODES ? hi : N_NODES];
  for (int i = beg + threadIdx.x; i < end; i += 1024) {
    unsigned int v = binned[i];
    int d = (int)(v & 0xFFFFu);
    int pos = atomicAdd(&cursor[d], 1);
    csr_src[pos] = (int)(v >> 16);
  }
}

// ---------------- layer 0 GEMM: h0 = x @ W0 (fp16 out), + fused attention dots ----------------
__global__ __launch_bounds__(256) void k_gemm0(
    const float* __restrict__ x, const float* __restrict__ W,
    const float* __restrict__ att_s, const float* __restrict__ att_d,
    __half* __restrict__ h, float* __restrict__ a_src, float* __restrict__ a_dst) {
  __shared__ float xs[64 * 132];
  int t = threadIdx.x;
  int rowBase = blockIdx.x * 64;
#pragma unroll
  for (int j = 0; j < 8; j++) {
    int id = t + 256 * j;
    int row = id >> 5;
    int kk = (id & 31) * 4;
    float4 v = make_float4(0.f, 0.f, 0.f, 0.f);
    int gr = rowBase + row;
    if (gr < N_NODES) v = *(const float4*)&x[(size_t)gr * 128 + kk];
    *(float4*)&xs[row * 132 + kk] = v;
  }
  __syncthreads();

  int tc = t & 31, tr = t >> 5;
  int c = tc * 4, r0 = tr * 8;
  float acc[8][4];
#pragma unroll
  for (int i = 0; i < 8; i++)
#pragma unroll
    for (int j = 0; j < 4; j++) acc[i][j] = 0.f;

  for (int k4 = 0; k4 < 128; k4 += 4) {
    float4 wv[4];
#pragma unroll
    for (int kk = 0; kk < 4; kk++) wv[kk] = *(const float4*)&W[(k4 + kk) * 128 + c];
    float4 xv[8];
#pragma unroll
    for (int i = 0; i < 8; i++) xv[i] = *(const float4*)&xs[(r0 + i) * 132 + k4];
#pragma unroll
    for (int i = 0; i < 8; i++) {
      acc[i][0] += xv[i].x * wv[0].x + xv[i].y * wv[1].x + xv[i].z * wv[2].x + xv[i].w * wv[3].x;
      acc[i][1] += xv[i].x * wv[0].y + xv[i].y * wv[1].y + xv[i].z * wv[2].y + xv[i].w * wv[3].y;
      acc[i][2] += xv[i].x * wv[0].z + xv[i].y * wv[1].z + xv[i].z * wv[2].z + xv[i].w * wv[3].z;
      acc[i][3] += xv[i].x * wv[0].w + xv[i].y * wv[1].w + xv[i].z * wv[2].w + xv[i].w * wv[3].w;
    }
  }

  float as4[4], ad4[4];
#pragma unroll
  for (int j = 0; j < 4; j++) { as4[j] = att_s[c + j]; ad4[j] = att_d[c + j]; }
  int head = tc >> 4;
#pragma unroll
  for (int i = 0; i < 8; i++) {
    int gr = rowBase + r0 + i;
    float ps = acc[i][0] * as4[0] + acc[i][1] * as4[1] + acc[i][2] * as4[2] + acc[i][3] * as4[3];
    float pd = acc[i][0] * ad4[0] + acc[i][1] * ad4[1] + acc[i][2] * ad4[2] + acc[i][3] * ad4[3];
#pragma unroll
    for (int msk = 1; msk <= 8; msk <<= 1) {
      ps += __shfl_xor(ps, msk);
      pd += __shfl_xor(pd, msk);
    }
    if (gr < N_NODES) {
      __half2 p01 = __floats2half2_rn(acc[i][0], acc[i][1]);
      __half2 p23 = __floats2half2_rn(acc[i][2], acc[i][3]);
      uint2 pk;
      pk.x = *(unsigned int*)&p01;
      pk.y = *(unsigned int*)&p23;
      *(uint2*)&h[(size_t)gr * 128 + c] = pk;
      if ((t & 15) == 0) {
        a_src[gr * 2 + head] = ps;
        a_dst[gr * 2 + head] = pd;
      }
    }
  }
}

// ---------------- layer 0 aggregation: wave per node, batched-8 online softmax, fp16 h --------
__global__ __launch_bounds__(256) void k_agg0(
    const int* __restrict__ row_ptr, const int* __restrict__ csr_src,
    const __half* __restrict__ h, const float* __restrict__ a_src,
    const float* __restrict__ a_dst, const float* __restrict__ bias,
    float* __restrict__ out) {
  int node = (blockIdx.x * blockDim.x + threadIdx.x) >> 6;
  if (node >= N_NODES) return;
  int l = threadIdx.x & 63;
  int head = l >> 5;
  int c = l * 2;
  float ad = a_dst[node * 2 + head];
  float m = lrelu(a_src[node * 2 + head] + ad);  // self-loop
  float d = 1.f;
  float2 hv = __half22float2(*(const __half2*)&h[(size_t)node * 128 + c]);
  float acc0 = hv.x, acc1 = hv.y;
  int beg = row_ptr[node], end = row_ptr[node + 1];
  int i = beg;
  for (; i + 8 <= end; i += 8) {
    int s0 = csr_src[i], s1 = csr_src[i + 1], s2 = csr_src[i + 2], s3 = csr_src[i + 3];
    int s4 = csr_src[i + 4], s5 = csr_src[i + 5], s6 = csr_src[i + 6], s7 = csr_src[i + 7];
    float e0 = lrelu(a_src[s0 * 2 + head] + ad), e1 = lrelu(a_src[s1 * 2 + head] + ad);
    float e2 = lrelu(a_src[s2 * 2 + head] + ad), e3 = lrelu(a_src[s3 * 2 + head] + ad);
    float e4 = lrelu(a_src[s4 * 2 + head] + ad), e5 = lrelu(a_src[s5 * 2 + head] + ad);
    float e6 = lrelu(a_src[s6 * 2 + head] + ad), e7 = lrelu(a_src[s7 * 2 + head] + ad);
    __half2 p0 = *(const __half2*)&h[(size_t)s0 * 128 + c];
    __half2 p1 = *(const __half2*)&h[(size_t)s1 * 128 + c];
    __half2 p2 = *(const __half2*)&h[(size_t)s2 * 128 + c];
    __half2 p3 = *(const __half2*)&h[(size_t)s3 * 128 + c];
    __half2 p4 = *(const __half2*)&h[(size_t)s4 * 128 + c];
    __half2 p5 = *(const __half2*)&h[(size_t)s5 * 128 + c];
    __half2 p6 = *(const __half2*)&h[(size_t)s6 * 128 + c];
    __half2 p7 = *(const __half2*)&h[(size_t)s7 * 128 + c];
    float nm = fmaxf(m, fmaxf(fmaxf(fmaxf(e0, e1), fmaxf(e2, e3)),
                              fmaxf(fmaxf(e4, e5), fmaxf(e6, e7))));
    float sc = __expf(m - nm);
    float w0 = __expf(e0 - nm), w1 = __expf(e1 - nm), w2 = __expf(e2 - nm), w3 = __expf(e3 - nm);
    float w4 = __expf(e4 - nm), w5 = __expf(e5 - nm), w6 = __expf(e6 - nm), w7 = __expf(e7 - nm);
    d = d * sc + ((w0 + w1) + (w2 + w3)) + ((w4 + w5) + (w6 + w7));
    float2 f0 = __half22float2(p0), f1 = __half22float2(p1);
    float2 f2 = __half22float2(p2), f3 = __half22float2(p3);
    float2 f4 = __half22float2(p4), f5 = __half22float2(p5);
    float2 f6 = __half22float2(p6), f7 = __half22float2(p7);
    acc0 = acc0 * sc + (w0 * f0.x + w1 * f1.x + w2 * f2.x + w3 * f3.x) +
           (w4 * f4.x + w5 * f5.x + w6 * f6.x + w7 * f7.x);
    acc1 = acc1 * sc + (w0 * f0.y + w1 * f1.y + w2 * f2.y + w3 * f3.y) +
           (w4 * f4.y + w5 * f5.y + w6 * f6.y + w7 * f7.y);
    m = nm;
  }
  for (; i + 4 <= end; i += 4) {
    int s0 = csr_src[i], s1 = csr_src[i + 1], s2 = csr_src[i + 2], s3 = csr_src[i + 3];
    float e0 = lrelu(a_src[s0 * 2 + head] + ad), e1 = lrelu(a_src[s1 * 2 + head] + ad);
    float e2 = lrelu(a_src[s2 * 2 + head] + ad), e3 = lrelu(a_src[s3 * 2 + head] + ad);
    __half2 p0 = *(const __half2*)&h[(size_t)s0 * 128 + c];
    __half2 p1 = *(const __half2*)&h[(size_t)s1 * 128 + c];
    __half2 p2 = *(const __half2*)&h[(size_t)s2 * 128 + c];
    __half2 p3 = *(const __half2*)&h[(size_t)s3 * 128 + c];
    float nm = fmaxf(fmaxf(m, e0), fmaxf(fmaxf(e1, e2), e3));
    float sc = __expf(m - nm);
    float w0 = __expf(e0 - nm), w1 = __expf(e1 - nm), w2 = __expf(e2 - nm), w3 = __expf(e3 - nm);
    d = d * sc + (w0 + w1) + (w2 + w3);
    float2 f0 = __half22float2(p0), f1 = __half22float2(p1);
    float2 f2 = __half22float2(p2), f3 = __half22float2(p3);
    acc0 = acc0 * sc + w0 * f0.x + w1 * f1.x + w2 * f2.x + w3 * f3.x;
    acc1 = acc1 * sc + w0 * f0.y + w1 * f1.y + w2 * f2.y + w3 * f3.y;
    m = nm;
  }
  for (; i < end; i++) {
    int s = csr_src[i];
    float ee = lrelu(a_src[s * 2 + head] + ad);
    __half2 pp = *(const __half2*)&h[(size_t)s * 128 + c];
    float nm = fmaxf(m, ee);
    float sc = __expf(m - nm);
    float w = __expf(ee - nm);
    float2 ff = __half22float2(pp);
    d = d * sc + w;
    acc0 = acc0 * sc + w * ff.x;
    acc1 = acc1 * sc + w * ff.y;
    m = nm;
  }
  float inv = 1.f / d;
  float2 o;
  o.x = acc0 * inv + bias[c];
  o.y = acc1 * inv + bias[c + 1];
  *(float2*)&out[(size_t)node * 128 + c] = o;
}

// ---------------- BatchNorm stats ----------------
__global__ __launch_bounds__(256) void k_bnstats(const float* __restrict__ x,
                                                 float* __restrict__ bn_sum,
                                                 float* __restrict__ bn_sumsq) {
  int f = threadIdx.x & 127;
  int half = threadIdx.x >> 7;
  float s = 0.f, s2 = 0.f;
  for (int r = blockIdx.x * 2 + half; r < N_NODES; r += gridDim.x * 2) {
    float v = x[(size_t)r * 128 + f];
    s += v;
    s2 += v * v;
  }
  __shared__ float ls[256], ls2[256];
  ls[threadIdx.x] = s;
  ls2[threadIdx.x] = s2;
  __syncthreads();
  if (half == 0) {
    atomicAdd(&bn_sum[f], s + ls[f + 128]);
    atomicAdd(&bn_sumsq[f], s2 + ls2[f + 128]);
  }
}

__global__ void k_bnfinal(const float* __restrict__ sum, const float* __restrict__ sumsq,
                          const float* __restrict__ gamma, const float* __restrict__ beta,
                          float* __restrict__ scale, float* __restrict__ shift) {
  int f = threadIdx.x;
  float mu = sum[f] / (float)N_NODES;
  float var = sumsq[f] / (float)N_NODES - mu * mu;
  float sc = gamma[f] * rsqrtf(var + BN_EPS);
  scale[f] = sc;
  shift[f] = beta[f] - mu * sc;
}

// ---------------- layer 1 GEMM (BN+ELU fused on load), fp16 h out ----------------
__global__ __launch_bounds__(256) void k_gemm1(
    const float* __restrict__ x, const float* __restrict__ W,
    const float* __restrict__ scale, const float* __restrict__ shift,
    const float* __restrict__ att_s, const float* __restrict__ att_d,
    __half* __restrict__ h, float* __restrict__ a_src, float* __restrict__ a_dst) {
  __shared__ float xs[64 * 132];
  int t = threadIdx.x;
  int rowBase = blockIdx.x * 64;
#pragma unroll
  for (int j = 0; j < 8; j++) {
    int id = t + 256 * j;
    int row = id >> 5;
    int kk = (id & 31) * 4;
    float4 v = make_float4(0.f, 0.f, 0.f, 0.f);
    int gr = rowBase + row;
    if (gr < N_NODES) {
      float4 raw = *(const float4*)&x[(size_t)gr * 128 + kk];
      float4 sc = *(const float4*)&scale[kk];
      float4 sh = *(const float4*)&shift[kk];
      v.x = raw.x * sc.x + sh.x;
      v.y = raw.y * sc.y + sh.y;
      v.z = raw.z * sc.z + sh.z;
      v.w = raw.w * sc.w + sh.w;
      v.x = v.x > 0.f ? v.x : __expf(v.x) - 1.f;
      v.y = v.y > 0.f ? v.y : __expf(v.y) - 1.f;
      v.z = v.z > 0.f ? v.z : __expf(v.z) - 1.f;
      v.w = v.w > 0.f ? v.w : __expf(v.w) - 1.f;
    }
    *(float4*)&xs[row * 132 + kk] = v;
  }
  __syncthreads();

  int tc = t & 15, tr = t >> 4;
  int c = tc * 4, r0 = tr * 4;
  float acc[4][4];
#pragma unroll
  for (int i = 0; i < 4; i++)
#pragma unroll
    for (int j = 0; j < 4; j++) acc[i][j] = 0.f;

  for (int k4 = 0; k4 < 128; k4 += 4) {
    float4 wv[4];
#pragma unroll
    for (int kk = 0; kk < 4; kk++) wv[kk] = *(const float4*)&W[(k4 + kk) * 64 + c];
    float4 xv[4];
#pragma unroll
    for (int i = 0; i < 4; i++) xv[i] = *(const float4*)&xs[(r0 + i) * 132 + k4];
#pragma unroll
    for (int i = 0; i < 4; i++) {
      acc[i][0] += xv[i].x * wv[0].x + xv[i].y * wv[1].x + xv[i].z * wv[2].x + xv[i].w * wv[3].x;
      acc[i][1] += xv[i].x * wv[0].y + xv[i].y * wv[1].y + xv[i].z * wv[2].y + xv[i].w * wv[3].y;
      acc[i][2] += xv[i].x * wv[0].z + xv[i].y * wv[1].z + xv[i].z * wv[2].z + xv[i].w * wv[3].z;
      acc[i][3] += xv[i].x * wv[0].w + xv[i].y * wv[1].w + xv[i].z * wv[2].w + xv[i].w * wv[3].w;
    }
  }

  float as4[4], ad4[4];
#pragma unroll
  for (int j = 0; j < 4; j++) { as4[j] = att_s[c + j]; ad4[j] = att_d[c + j]; }
#pragma unroll
  for (int i = 0; i < 4; i++) {
    int gr = rowBase + r0 + i;
    float ps = acc[i][0] * as4[0] + acc[i][1] * as4[1] + acc[i][2] * as4[2] + acc[i][3] * as4[3];
    float pd = acc[i][0] * ad4[0] + acc[i][1] * ad4[1] + acc[i][2] * ad4[2] + acc[i][3] * ad4[3];
#pragma unroll
    for (int msk = 1; msk <= 8; msk <<= 1) {
      ps += __shfl_xor(ps, msk);
      pd += __shfl_xor(pd, msk);
    }
    if (gr < N_NODES) {
      __half2 p01 = __floats2half2_rn(acc[i][0], acc[i][1]);
      __half2 p23 = __floats2half2_rn(acc[i][2], acc[i][3]);
      uint2 pk;
      pk.x = *(unsigned int*)&p01;
      pk.y = *(unsigned int*)&p23;
      *(uint2*)&h[(size_t)gr * 64 + c] = pk;
      if ((t & 15) == 0) {
        a_src[gr] = ps;
        a_dst[gr] = pd;
      }
    }
  }
}

// ---------------- layer 1 aggregation: batched-8, fp16 h ----------------
__global__ __launch_bounds__(256) void k_agg1(
    const int* __restrict__ row_ptr, const int* __restrict__ csr_src,
    const __half* __restrict__ h, const float* __restrict__ a_src,
    const float* __restrict__ a_dst, const float* __restrict__ bias,
    float* __restrict__ out) {
  int node = (blockIdx.x * blockDim.x + threadIdx.x) >> 6;
  if (node >= N_NODES) return;
  int l = threadIdx.x & 63;
  float ad = a_dst[node];
  float m = lrelu(a_src[node] + ad);  // self loop
  float d = 1.f;
  float acc = __half2float(h[(size_t)node * 64 + l]);
  int beg = row_ptr[node], end = row_ptr[node + 1];
  int i = beg;
  for (; i + 8 <= end; i += 8) {
    int s0 = csr_src[i], s1 = csr_src[i + 1], s2 = csr_src[i + 2], s3 = csr_src[i + 3];
    int s4 = csr_src[i + 4], s5 = csr_src[i + 5], s6 = csr_src[i + 6], s7 = csr_src[i + 7];
    float e0 = lrelu(a_src[s0] + ad), e1 = lrelu(a_src[s1] + ad);
    float e2 = lrelu(a_src[s2] + ad), e3 = lrelu(a_src[s3] + ad);
    float e4 = lrelu(a_src[s4] + ad), e5 = lrelu(a_src[s5] + ad);
    float e6 = lrelu(a_src[s6] + ad), e7 = lrelu(a_src[s7] + ad);
    __half p0 = h[(size_t)s0 * 64 + l], p1 = h[(size_t)s1 * 64 + l];
    __half p2 = h[(size_t)s2 * 64 + l], p3 = h[(size_t)s3 * 64 + l];
    __half p4 = h[(size_t)s4 * 64 + l], p5 = h[(size_t)s5 * 64 + l];
    __half p6 = h[(size_t)s6 * 64 + l], p7 = h[(size_t)s7 * 64 + l];
    float nm = fmaxf(m, fmaxf(fmaxf(fmaxf(e0, e1), fmaxf(e2, e3)),
                              fmaxf(fmaxf(e4, e5), fmaxf(e6, e7))));
    float sc = __expf(m - nm);
    float w0 = __expf(e0 - nm), w1 = __expf(e1 - nm), w2 = __expf(e2 - nm), w3 = __expf(e3 - nm);
    float w4 = __expf(e4 - nm), w5 = __expf(e5 - nm), w6 = __expf(e6 - nm), w7 = __expf(e7 - nm);
    d = d * sc + ((w0 + w1) + (w2 + w3)) + ((w4 + w5) + (w6 + w7));
    acc = acc * sc +
          (w0 * __half2float(p0) + w1 * __half2float(p1) + w2 * __half2float(p2) +
           w3 * __half2float(p3)) +
          (w4 * __half2float(p4) + w5 * __half2float(p5) + w6 * __half2float(p6) +
           w7 * __half2float(p7));
    m = nm;
  }
  for (; i + 4 <= end; i += 4) {
    int s0 = csr_src[i], s1 = csr_src[i + 1], s2 = csr_src[i + 2], s3 = csr_src[i + 3];
    float e0 = lrelu(a_src[s0] + ad), e1 = lrelu(a_src[s1] + ad);
    float e2 = lrelu(a_src[s2] + ad), e3 = lrelu(a_src[s3] + ad);
    __half p0 = h[(size_t)s0 * 64 + l], p1 = h[(size_t)s1 * 64 + l];
    __half p2 = h[(size_t)s2 * 64 + l], p3 = h[(size_t)s3 * 64 + l];
    float nm = fmaxf(fmaxf(m, e0), fmaxf(fmaxf(e1, e2), e3));
    float sc = __expf(m - nm);
    float w0 = __expf(e0 - nm), w1 = __expf(e1 - nm), w2 = __expf(e2 - nm), w3 = __expf(e3 - nm);
    d = d * sc + (w0 + w1) + (w2 + w3);
    acc = acc * sc + w0 * __half2float(p0) + w1 * __half2float(p1) + w2 * __half2float(p2) +
          w3 * __half2float(p3);
    m = nm;
  }
  for (; i < end; i++) {
    int s = csr_src[i];
    float ee = lrelu(a_src[s] + ad);
    __half pp = h[(size_t)s * 64 + l];
    float nm = fmaxf(m, ee);
    float sc = __expf(m - nm);
    float w = __expf(ee - nm);
    d = d * sc + w;
    acc = acc * sc + w * __half2float(pp);
    m = nm;
  }
  out[(size_t)node * 64 + l] = acc / d + bias[l];
}

// ---------------- launch ----------------
extern "C" void kernel_launch(void* const* d_in, const int* in_sizes, int n_in,
                              void* d_out, int out_size, void* d_ws, size_t ws_size,
                              hipStream_t stream) {
  const float* data = (const float*)d_in[0];
  const int* ei = (const int*)d_in[1];
  const float* W0 = (const float*)d_in[2];
  const float* att_src0 = (const float*)d_in[3];
  const float* att_dst0 = (const float*)d_in[4];
  const float* bias0 = (const float*)d_in[5];
  const float* gamma0 = (const float*)d_in[6];
  const float* beta0 = (const float*)d_in[7];
  const float* W1 = (const float*)d_in[8];
  const float* att_src1 = (const float*)d_in[9];
  const float* att_dst1 = (const float*)d_in[10];
  const float* bias1 = (const float*)d_in[11];
  float* out = (float*)d_out;

  char* ws = (char*)d_ws;
  size_t off = 0;
  auto alloc = [&](size_t bytes) -> void* {
    void* p = ws + off;
    off = (off + bytes + 255) & ~(size_t)255;
    return p;
  };
  int* row_ptr = (int*)alloc((N_NODES + 1) * 4);
  int* counts = (int*)alloc((N_NODES + 1) * 4);
  int* cursor = (int*)alloc(N_NODES * 4);
  int* tmp_scan = (int*)alloc((size_t)N_NODES * 4);
  int* blk_sums = (int*)alloc(64 * 4);
  int* bin_cursor = (int*)alloc(NB * 4);
  unsigned int* binned = (unsigned int*)alloc((size_t)E_EDGES * 4);
  int* csr_src = (int*)alloc((size_t)E_EDGES * 4);
  __half* h0 = (__half*)alloc((size_t)N_NODES * 128 * 2);  // fp16 h
  float* a_s0 = (float*)alloc((size_t)N_NODES * 2 * 4);
  float* a_d0 = (float*)alloc((size_t)N_NODES * 2 * 4);
  float* out0 = (float*)alloc((size_t)N_NODES * 128 * 4);
  float* bn_sum = (float*)alloc(128 * 4);
  float* bn_sumsq = (float*)alloc(128 * 4);
  float* bn_scale = (float*)alloc(128 * 4);
  float* bn_shift = (float*)alloc(128 * 4);
  __half* h1 = h0;   // layer-1 buffers alias dead layer-0 buffers
  float* a_s1 = a_s0;
  float* a_d1 = a_d0;

  const int* srcArr = ei;
  const int* dstArr = ei + E_EDGES;

  k_zero<<<(N_NODES + 256) / 256, 256, 0, stream>>>(counts, bn_sum, bn_sumsq);
  k_hist<<<(E_EDGES + 255) / 256, 256, 0, stream>>>(dstArr, counts);
  k_scan1<<<SCAN_NBLK, 256, 0, stream>>>(counts, tmp_scan, blk_sums);
  k_scan2<<<1, 64, 0, stream>>>(blk_sums);
  k_scan3<<<(N_NODES + 255) / 256, 256, 0, stream>>>(tmp_scan, blk_sums, row_ptr, cursor,
                                                     bin_cursor);
  k_bin<<<BIN_NBLK, 256, 0, stream>>>(srcArr, dstArr, bin_cursor, binned);
  k_scatter2<<<NB, 1024, 0, stream>>>(row_ptr, binned, cursor, csr_src);
  k_gemm0<<<(N_NODES + 63) / 64, 256, 0, stream>>>(data, W0, att_src0, att_dst0, h0, a_s0, a_d0);
  k_agg0<<<(N_NODES + 3) / 4, 256, 0, stream>>>(row_ptr, csr_src, h0, a_s0, a_d0, bias0, out0);
  k_bnstats<<<1024, 256, 0, stream>>>(out0, bn_sum, bn_sumsq);
  k_bnfinal<<<1, 128, 0, stream>>>(bn_sum, bn_sumsq, gamma0, beta0, bn_scale, bn_shift);
  k_gemm1<<<(N_NODES + 63) / 64, 256, 0, stream>>>(out0, W1, bn_scale, bn_shift, att_src1,
                                                   att_dst1, h1, a_s1, a_d1);
  k_agg1<<<(N_NODES + 3) / 4, 256, 0, stream>>>(row_ptr, csr_src, h1, a_s1, a_d1, bias1, out);
}

// Round 6
// 381.087 us; speedup vs baseline: 1.1111x; 1.1111x over previous
//
#include <hip/hip_runtime.h>
#include <hip/hip_fp16.h>
#include <math.h>

#define N_NODES 50000
#define E_EDGES 800000
#define NEG_SLOPE 0.2f
#define BN_EPS 1e-5f

#define BK_SHIFT 9                     // 512-node buckets
#define NBK 98                         // ceil(50000/512)
#define BIN_K 160                      // LDS entries per bin
#define BIN_FLUSH 32                   // flush threshold; invariant fill<32 at tile start, +128 <= 159 < 160
#define BIN_TILE 128
#define BIN_BLOCKS 128
#define BIN_CHUNK (E_EDGES / BIN_BLOCKS)  // 6250 exactly
#define STAGE_MAX 9216                 // per-bucket staging (mean 8192, +11 sigma)

__device__ __forceinline__ float lrelu(float v) { return v > 0.f ? v : NEG_SLOPE * v; }

// ---------------- init ----------------
__global__ void k_zero(int* __restrict__ bucket_cnt, float* __restrict__ bn_sum,
                       float* __restrict__ bn_sumsq) {
  int t = threadIdx.x;
  if (t < NBK) bucket_cnt[t] = 0;
  if (t < 128) { bn_sum[t] = 0.f; bn_sumsq[t] = 0.f; }
}

// ---------------- bucket histogram (LDS, 1 global atomic per bucket per block) ----------------
__global__ __launch_bounds__(256) void k_histB(const int* __restrict__ dst,
                                               int* __restrict__ bucket_cnt) {
  __shared__ int lcnt[NBK];
  int t = threadIdx.x;
  if (t < NBK) lcnt[t] = 0;
  __syncthreads();
  for (int e = blockIdx.x * 256 + t; e < E_EDGES; e += gridDim.x * 256)
    atomicAdd(&lcnt[((unsigned int)dst[e]) >> BK_SHIFT], 1);
  __syncthreads();
  if (t < NBK) atomicAdd(&bucket_cnt[t], lcnt[t]);
}

// ---------------- bucket scan: 99-entry exclusive scan in one wave ----------------
__global__ void k_scanB(const int* __restrict__ bucket_cnt, int* __restrict__ bucket_base,
                        int* __restrict__ bin_cursor) {
  int t = threadIdx.x;  // 64 lanes, 2 elements each
  int i0 = 2 * t, i1 = 2 * t + 1;
  int c0 = (i0 < NBK) ? bucket_cnt[i0] : 0;
  int c1 = (i1 < NBK) ? bucket_cnt[i1] : 0;
  int pair = c0 + c1;
  int v = pair;
#pragma unroll
  for (int off = 1; off < 64; off <<= 1) {
    int u = __shfl_up(v, off);
    if (t >= off) v += u;
  }
  int excl = v - pair;
  if (i0 < NBK + 1) { bucket_base[i0] = excl; if (i0 < NBK) bin_cursor[i0] = excl; }
  if (i1 < NBK + 1) { bucket_base[i1] = excl + c0; if (i1 < NBK) bin_cursor[i1] = excl + c0; }
}

// ---------------- pass 1: LDS multisplit into 98 bins; packed (src<<16)|dst ----------------
__global__ __launch_bounds__(256) void k_bin(const int* __restrict__ src,
                                             const int* __restrict__ dst,
                                             int* __restrict__ bin_cursor,
                                             unsigned int* __restrict__ binned) {
  __shared__ unsigned int bins[NBK][BIN_K];  // 62720 B
  __shared__ int fill[NBK];
  __shared__ int flushbase[NBK];
  __shared__ int flushlist[NBK];
  __shared__ int nflush;
  int t = threadIdx.x;
  if (t < NBK) fill[t] = 0;
  __syncthreads();
  int chunkBeg = blockIdx.x * BIN_CHUNK;
  int chunkEnd = chunkBeg + BIN_CHUNK;
  for (int base = chunkBeg; base < chunkEnd; base += BIN_TILE) {
    int e = base + t;
    if (t < BIN_TILE && e < chunkEnd) {
      unsigned int d = (unsigned int)dst[e];
      int b = d >> BK_SHIFT;
      int pos = atomicAdd(&fill[b], 1);
      bins[b][pos] = ((unsigned int)src[e] << 16) | d;
    }
    if (t == 0) nflush = 0;
    __syncthreads();
    if (t < NBK) {
      int f = fill[t];
      if (f >= BIN_FLUSH) {
        flushbase[t] = atomicAdd(&bin_cursor[t], f);
        int idx = atomicAdd(&nflush, 1);
        flushlist[idx] = t;
      }
    }
    __syncthreads();
    int nf = nflush;
    for (int j = 0; j < nf; j++) {
      int b = flushlist[j];
      int f = fill[b];
      int fb = flushbase[b];
      for (int k = t; k < f; k += 256) binned[fb + k] = bins[b][k];
    }
    __syncthreads();
    if (t < nf) fill[flushlist[t]] = 0;
    __syncthreads();
  }
  // final flush (all remaining)
  if (t < NBK) {
    int f = fill[t];
    flushbase[t] = (f > 0) ? atomicAdd(&bin_cursor[t], f) : -1;
  }
  __syncthreads();
  for (int b = 0; b < NBK; b++) {
    int fb = flushbase[b];
    if (fb >= 0) {
      int f = fill[b];
      for (int k = t; k < f; k += 256) binned[fb + k] = bins[b][k];
    }
  }
}

// ---------------- pass 2: per-bucket LDS counting sort; coalesced csr writes + row_ptr -------
__global__ __launch_bounds__(256) void k_scatter3(const int* __restrict__ bucket_base,
                                                  const unsigned int* __restrict__ binned,
                                                  int* __restrict__ row_ptr,
                                                  int* __restrict__ csr_src) {
  __shared__ int cnt[512];
  __shared__ int staging[STAGE_MAX];  // 36 KB
  __shared__ int ts[256];
  int t = threadIdx.x;
  int b = blockIdx.x;
  int lo = b << BK_SHIFT;
  int hi = lo + 512; if (hi > N_NODES) hi = N_NODES;
  int nloc = hi - lo;
  int base = bucket_base[b];
  int end = bucket_base[b + 1];
  cnt[t] = 0; cnt[t + 256] = 0;
  __syncthreads();
  // pass A: local per-node histogram
  for (int i = base + t; i < end; i += 256)
    atomicAdd(&cnt[(binned[i] & 0xFFFFu) - lo], 1);
  __syncthreads();
  // exclusive scan of 512 counters (2 per thread)
  int c0 = cnt[2 * t], c1 = cnt[2 * t + 1];
  int pair = c0 + c1;
  ts[t] = pair;
  __syncthreads();
  for (int off = 1; off < 256; off <<= 1) {
    int v = (t >= off) ? ts[t - off] : 0;
    __syncthreads();
    ts[t] += v;
    __syncthreads();
  }
  int exclp = ts[t] - pair;
  cnt[2 * t] = exclp;
  cnt[2 * t + 1] = exclp + c0;
  if (2 * t < nloc) row_ptr[lo + 2 * t] = base + exclp;
  if (2 * t + 1 < nloc) row_ptr[lo + 2 * t + 1] = base + exclp + c0;
  if (b == NBK - 1 && t == 0) row_ptr[N_NODES] = E_EDGES;
  __syncthreads();
  // pass B: place into LDS staging via LDS cursors
  for (int i = base + t; i < end; i += 256) {
    unsigned int v = binned[i];
    int d = (int)(v & 0xFFFFu) - lo;
    int p = atomicAdd(&cnt[d], 1);
    int s = (int)(v >> 16);
    if (p < STAGE_MAX) staging[p] = s;
    else csr_src[base + p] = s;  // overflow fallback (correct, uncoalesced)
  }
  __syncthreads();
  // coalesced write-out
  int tot = end - base;
  int lim = tot < STAGE_MAX ? tot : STAGE_MAX;
  for (int k = t; k < lim; k += 256) csr_src[base + k] = staging[k];
}

// ---------------- layer 0 GEMM: h0 = x @ W0 (fp16 out), + fused attention dots ----------------
__global__ __launch_bounds__(256) void k_gemm0(
    const float* __restrict__ x, const float* __restrict__ W,
    const float* __restrict__ att_s, const float* __restrict__ att_d,
    __half* __restrict__ h, float* __restrict__ a_src, float* __restrict__ a_dst) {
  __shared__ float xs[64 * 132];
  int t = threadIdx.x;
  int rowBase = blockIdx.x * 64;
#pragma unroll
  for (int j = 0; j < 8; j++) {
    int id = t + 256 * j;
    int row = id >> 5;
    int kk = (id & 31) * 4;
    float4 v = make_float4(0.f, 0.f, 0.f, 0.f);
    int gr = rowBase + row;
    if (gr < N_NODES) v = *(const float4*)&x[(size_t)gr * 128 + kk];
    *(float4*)&xs[row * 132 + kk] = v;
  }
  __syncthreads();

  int tc = t & 31, tr = t >> 5;
  int c = tc * 4, r0 = tr * 8;
  float acc[8][4];
#pragma unroll
  for (int i = 0; i < 8; i++)
#pragma unroll
    for (int j = 0; j < 4; j++) acc[i][j] = 0.f;

  for (int k4 = 0; k4 < 128; k4 += 4) {
    float4 wv[4];
#pragma unroll
    for (int kk = 0; kk < 4; kk++) wv[kk] = *(const float4*)&W[(k4 + kk) * 128 + c];
    float4 xv[8];
#pragma unroll
    for (int i = 0; i < 8; i++) xv[i] = *(const float4*)&xs[(r0 + i) * 132 + k4];
#pragma unroll
    for (int i = 0; i < 8; i++) {
      acc[i][0] += xv[i].x * wv[0].x + xv[i].y * wv[1].x + xv[i].z * wv[2].x + xv[i].w * wv[3].x;
      acc[i][1] += xv[i].x * wv[0].y + xv[i].y * wv[1].y + xv[i].z * wv[2].y + xv[i].w * wv[3].y;
      acc[i][2] += xv[i].x * wv[0].z + xv[i].y * wv[1].z + xv[i].z * wv[2].z + xv[i].w * wv[3].z;
      acc[i][3] += xv[i].x * wv[0].w + xv[i].y * wv[1].w + xv[i].z * wv[2].w + xv[i].w * wv[3].w;
    }
  }

  float as4[4], ad4[4];
#pragma unroll
  for (int j = 0; j < 4; j++) { as4[j] = att_s[c + j]; ad4[j] = att_d[c + j]; }
  int head = tc >> 4;
#pragma unroll
  for (int i = 0; i < 8; i++) {
    int gr = rowBase + r0 + i;
    float ps = acc[i][0] * as4[0] + acc[i][1] * as4[1] + acc[i][2] * as4[2] + acc[i][3] * as4[3];
    float pd = acc[i][0] * ad4[0] + acc[i][1] * ad4[1] + acc[i][2] * ad4[2] + acc[i][3] * ad4[3];
#pragma unroll
    for (int msk = 1; msk <= 8; msk <<= 1) {
      ps += __shfl_xor(ps, msk);
      pd += __shfl_xor(pd, msk);
    }
    if (gr < N_NODES) {
      __half2 p01 = __floats2half2_rn(acc[i][0], acc[i][1]);
      __half2 p23 = __floats2half2_rn(acc[i][2], acc[i][3]);
      uint2 pk;
      pk.x = *(unsigned int*)&p01;
      pk.y = *(unsigned int*)&p23;
      *(uint2*)&h[(size_t)gr * 128 + c] = pk;
      if ((t & 15) == 0) {
        a_src[gr * 2 + head] = ps;
        a_dst[gr * 2 + head] = pd;
      }
    }
  }
}

// ---------------- layer 0 aggregation: wave per node, batched-8 online softmax, fp16 h --------
__global__ __launch_bounds__(256) void k_agg0(
    const int* __restrict__ row_ptr, const int* __restrict__ csr_src,
    const __half* __restrict__ h, const float* __restrict__ a_src,
    const float* __restrict__ a_dst, const float* __restrict__ bias,
    float* __restrict__ out) {
  int node = (blockIdx.x * blockDim.x + threadIdx.x) >> 6;
  if (node >= N_NODES) return;
  int l = threadIdx.x & 63;
  int head = l >> 5;
  int c = l * 2;
  float ad = a_dst[node * 2 + head];
  float m = lrelu(a_src[node * 2 + head] + ad);  // self-loop
  float d = 1.f;
  float2 hv = __half22float2(*(const __half2*)&h[(size_t)node * 128 + c]);
  float acc0 = hv.x, acc1 = hv.y;
  int beg = row_ptr[node], end = row_ptr[node + 1];
  int i = beg;
  for (; i + 8 <= end; i += 8) {
    int s0 = csr_src[i], s1 = csr_src[i + 1], s2 = csr_src[i + 2], s3 = csr_src[i + 3];
    int s4 = csr_src[i + 4], s5 = csr_src[i + 5], s6 = csr_src[i + 6], s7 = csr_src[i + 7];
    float e0 = lrelu(a_src[s0 * 2 + head] + ad), e1 = lrelu(a_src[s1 * 2 + head] + ad);
    float e2 = lrelu(a_src[s2 * 2 + head] + ad), e3 = lrelu(a_src[s3 * 2 + head] + ad);
    float e4 = lrelu(a_src[s4 * 2 + head] + ad), e5 = lrelu(a_src[s5 * 2 + head] + ad);
    float e6 = lrelu(a_src[s6 * 2 + head] + ad), e7 = lrelu(a_src[s7 * 2 + head] + ad);
    __half2 p0 = *(const __half2*)&h[(size_t)s0 * 128 + c];
    __half2 p1 = *(const __half2*)&h[(size_t)s1 * 128 + c];
    __half2 p2 = *(const __half2*)&h[(size_t)s2 * 128 + c];
    __half2 p3 = *(const __half2*)&h[(size_t)s3 * 128 + c];
    __half2 p4 = *(const __half2*)&h[(size_t)s4 * 128 + c];
    __half2 p5 = *(const __half2*)&h[(size_t)s5 * 128 + c];
    __half2 p6 = *(const __half2*)&h[(size_t)s6 * 128 + c];
    __half2 p7 = *(const __half2*)&h[(size_t)s7 * 128 + c];
    float nm = fmaxf(m, fmaxf(fmaxf(fmaxf(e0, e1), fmaxf(e2, e3)),
                              fmaxf(fmaxf(e4, e5), fmaxf(e6, e7))));
    float sc = __expf(m - nm);
    float w0 = __expf(e0 - nm), w1 = __expf(e1 - nm), w2 = __expf(e2 - nm), w3 = __expf(e3 - nm);
    float w4 = __expf(e4 - nm), w5 = __expf(e5 - nm), w6 = __expf(e6 - nm), w7 = __expf(e7 - nm);
    d = d * sc + ((w0 + w1) + (w2 + w3)) + ((w4 + w5) + (w6 + w7));
    float2 f0 = __half22float2(p0), f1 = __half22float2(p1);
    float2 f2 = __half22float2(p2), f3 = __half22float2(p3);
    float2 f4 = __half22float2(p4), f5 = __half22float2(p5);
    float2 f6 = __half22float2(p6), f7 = __half22float2(p7);
    acc0 = acc0 * sc + (w0 * f0.x + w1 * f1.x + w2 * f2.x + w3 * f3.x) +
           (w4 * f4.x + w5 * f5.x + w6 * f6.x + w7 * f7.x);
    acc1 = acc1 * sc + (w0 * f0.y + w1 * f1.y + w2 * f2.y + w3 * f3.y) +
           (w4 * f4.y + w5 * f5.y + w6 * f6.y + w7 * f7.y);
    m = nm;
  }
  for (; i + 4 <= end; i += 4) {
    int s0 = csr_src[i], s1 = csr_src[i + 1], s2 = csr_src[i + 2], s3 = csr_src[i + 3];
    float e0 = lrelu(a_src[s0 * 2 + head] + ad), e1 = lrelu(a_src[s1 * 2 + head] + ad);
    float e2 = lrelu(a_src[s2 * 2 + head] + ad), e3 = lrelu(a_src[s3 * 2 + head] + ad);
    __half2 p0 = *(const __half2*)&h[(size_t)s0 * 128 + c];
    __half2 p1 = *(const __half2*)&h[(size_t)s1 * 128 + c];
    __half2 p2 = *(const __half2*)&h[(size_t)s2 * 128 + c];
    __half2 p3 = *(const __half2*)&h[(size_t)s3 * 128 + c];
    float nm = fmaxf(fmaxf(m, e0), fmaxf(fmaxf(e1, e2), e3));
    float sc = __expf(m - nm);
    float w0 = __expf(e0 - nm), w1 = __expf(e1 - nm), w2 = __expf(e2 - nm), w3 = __expf(e3 - nm);
    d = d * sc + (w0 + w1) + (w2 + w3);
    float2 f0 = __half22float2(p0), f1 = __half22float2(p1);
    float2 f2 = __half22float2(p2), f3 = __half22float2(p3);
    acc0 = acc0 * sc + w0 * f0.x + w1 * f1.x + w2 * f2.x + w3 * f3.x;
    acc1 = acc1 * sc + w0 * f0.y + w1 * f1.y + w2 * f2.y + w3 * f3.y;
    m = nm;
  }
  for (; i < end; i++) {
    int s = csr_src[i];
    float ee = lrelu(a_src[s * 2 + head] + ad);
    __half2 pp = *(const __half2*)&h[(size_t)s * 128 + c];
    float nm = fmaxf(m, ee);
    float sc = __expf(m - nm);
    float w = __expf(ee - nm);
    float2 ff = __half22float2(pp);
    d = d * sc + w;
    acc0 = acc0 * sc + w * ff.x;
    acc1 = acc1 * sc + w * ff.y;
    m = nm;
  }
  float inv = 1.f / d;
  float2 o;
  o.x = acc0 * inv + bias[c];
  o.y = acc1 * inv + bias[c + 1];
  *(float2*)&out[(size_t)node * 128 + c] = o;
}

// ---------------- BatchNorm stats ----------------
__global__ __launch_bounds__(256) void k_bnstats(const float* __restrict__ x,
                                                 float* __restrict__ bn_sum,
                                                 float* __restrict__ bn_sumsq) {
  int f = threadIdx.x & 127;
  int half = threadIdx.x >> 7;
  float s = 0.f, s2 = 0.f;
  for (int r = blockIdx.x * 2 + half; r < N_NODES; r += gridDim.x * 2) {
    float v = x[(size_t)r * 128 + f];
    s += v;
    s2 += v * v;
  }
  __shared__ float ls[256], ls2[256];
  ls[threadIdx.x] = s;
  ls2[threadIdx.x] = s2;
  __syncthreads();
  if (half == 0) {
    atomicAdd(&bn_sum[f], s + ls[f + 128]);
    atomicAdd(&bn_sumsq[f], s2 + ls2[f + 128]);
  }
}

__global__ void k_bnfinal(const float* __restrict__ sum, const float* __restrict__ sumsq,
                          const float* __restrict__ gamma, const float* __restrict__ beta,
                          float* __restrict__ scale, float* __restrict__ shift) {
  int f = threadIdx.x;
  float mu = sum[f] / (float)N_NODES;
  float var = sumsq[f] / (float)N_NODES - mu * mu;
  float sc = gamma[f] * rsqrtf(var + BN_EPS);
  scale[f] = sc;
  shift[f] = beta[f] - mu * sc;
}

// ---------------- layer 1 GEMM (BN+ELU fused on load), fp16 h out ----------------
__global__ __launch_bounds__(256) void k_gemm1(
    const float* __restrict__ x, const float* __restrict__ W,
    const float* __restrict__ scale, const float* __restrict__ shift,
    const float* __restrict__ att_s, const float* __restrict__ att_d,
    __half* __restrict__ h, float* __restrict__ a_src, float* __restrict__ a_dst) {
  __shared__ float xs[64 * 132];
  int t = threadIdx.x;
  int rowBase = blockIdx.x * 64;
#pragma unroll
  for (int j = 0; j < 8; j++) {
    int id = t + 256 * j;
    int row = id >> 5;
    int kk = (id & 31) * 4;
    float4 v = make_float4(0.f, 0.f, 0.f, 0.f);
    int gr = rowBase + row;
    if (gr < N_NODES) {
      float4 raw = *(const float4*)&x[(size_t)gr * 128 + kk];
      float4 sc = *(const float4*)&scale[kk];
      float4 sh = *(const float4*)&shift[kk];
      v.x = raw.x * sc.x + sh.x;
      v.y = raw.y * sc.y + sh.y;
      v.z = raw.z * sc.z + sh.z;
      v.w = raw.w * sc.w + sh.w;
      v.x = v.x > 0.f ? v.x : __expf(v.x) - 1.f;
      v.y = v.y > 0.f ? v.y : __expf(v.y) - 1.f;
      v.z = v.z > 0.f ? v.z : __expf(v.z) - 1.f;
      v.w = v.w > 0.f ? v.w : __expf(v.w) - 1.f;
    }
    *(float4*)&xs[row * 132 + kk] = v;
  }
  __syncthreads();

  int tc = t & 15, tr = t >> 4;
  int c = tc * 4, r0 = tr * 4;
  float acc[4][4];
#pragma unroll
  for (int i = 0; i < 4; i++)
#pragma unroll
    for (int j = 0; j < 4; j++) acc[i][j] = 0.f;

  for (int k4 = 0; k4 < 128; k4 += 4) {
    float4 wv[4];
#pragma unroll
    for (int kk = 0; kk < 4; kk++) wv[kk] = *(const float4*)&W[(k4 + kk) * 64 + c];
    float4 xv[4];
#pragma unroll
    for (int i = 0; i < 4; i++) xv[i] = *(const float4*)&xs[(r0 + i) * 132 + k4];
#pragma unroll
    for (int i = 0; i < 4; i++) {
      acc[i][0] += xv[i].x * wv[0].x + xv[i].y * wv[1].x + xv[i].z * wv[2].x + xv[i].w * wv[3].x;
      acc[i][1] += xv[i].x * wv[0].y + xv[i].y * wv[1].y + xv[i].z * wv[2].y + xv[i].w * wv[3].y;
      acc[i][2] += xv[i].x * wv[0].z + xv[i].y * wv[1].z + xv[i].z * wv[2].z + xv[i].w * wv[3].z;
      acc[i][3] += xv[i].x * wv[0].w + xv[i].y * wv[1].w + xv[i].z * wv[2].w + xv[i].w * wv[3].w;
    }
  }

  float as4[4], ad4[4];
#pragma unroll
  for (int j = 0; j < 4; j++) { as4[j] = att_s[c + j]; ad4[j] = att_d[c + j]; }
#pragma unroll
  for (int i = 0; i < 4; i++) {
    int gr = rowBase + r0 + i;
    float ps = acc[i][0] * as4[0] + acc[i][1] * as4[1] + acc[i][2] * as4[2] + acc[i][3] * as4[3];
    float pd = acc[i][0] * ad4[0] + acc[i][1] * ad4[1] + acc[i][2] * ad4[2] + acc[i][3] * ad4[3];
#pragma unroll
    for (int msk = 1; msk <= 8; msk <<= 1) {
      ps += __shfl_xor(ps, msk);
      pd += __shfl_xor(pd, msk);
    }
    if (gr < N_NODES) {
      __half2 p01 = __floats2half2_rn(acc[i][0], acc[i][1]);
      __half2 p23 = __floats2half2_rn(acc[i][2], acc[i][3]);
      uint2 pk;
      pk.x = *(unsigned int*)&p01;
      pk.y = *(unsigned int*)&p23;
      *(uint2*)&h[(size_t)gr * 64 + c] = pk;
      if ((t & 15) == 0) {
        a_src[gr] = ps;
        a_dst[gr] = pd;
      }
    }
  }
}

// ---------------- layer 1 aggregation: batched-8, fp16 h ----------------
__global__ __launch_bounds__(256) void k_agg1(
    const int* __restrict__ row_ptr, const int* __restrict__ csr_src,
    const __half* __restrict__ h, const float* __restrict__ a_src,
    const float* __restrict__ a_dst, const float* __restrict__ bias,
    float* __restrict__ out) {
  int node = (blockIdx.x * blockDim.x + threadIdx.x) >> 6;
  if (node >= N_NODES) return;
  int l = threadIdx.x & 63;
  float ad = a_dst[node];
  float m = lrelu(a_src[node] + ad);  // self loop
  float d = 1.f;
  float acc = __half2float(h[(size_t)node * 64 + l]);
  int beg = row_ptr[node], end = row_ptr[node + 1];
  int i = beg;
  for (; i + 8 <= end; i += 8) {
    int s0 = csr_src[i], s1 = csr_src[i + 1], s2 = csr_src[i + 2], s3 = csr_src[i + 3];
    int s4 = csr_src[i + 4], s5 = csr_src[i + 5], s6 = csr_src[i + 6], s7 = csr_src[i + 7];
    float e0 = lrelu(a_src[s0] + ad), e1 = lrelu(a_src[s1] + ad);
    float e2 = lrelu(a_src[s2] + ad), e3 = lrelu(a_src[s3] + ad);
    float e4 = lrelu(a_src[s4] + ad), e5 = lrelu(a_src[s5] + ad);
    float e6 = lrelu(a_src[s6] + ad), e7 = lrelu(a_src[s7] + ad);
    __half p0 = h[(size_t)s0 * 64 + l], p1 = h[(size_t)s1 * 64 + l];
    __half p2 = h[(size_t)s2 * 64 + l], p3 = h[(size_t)s3 * 64 + l];
    __half p4 = h[(size_t)s4 * 64 + l], p5 = h[(size_t)s5 * 64 + l];
    __half p6 = h[(size_t)s6 * 64 + l], p7 = h[(size_t)s7 * 64 + l];
    float nm = fmaxf(m, fmaxf(fmaxf(fmaxf(e0, e1), fmaxf(e2, e3)),
                              fmaxf(fmaxf(e4, e5), fmaxf(e6, e7))));
    float sc = __expf(m - nm);
    float w0 = __expf(e0 - nm), w1 = __expf(e1 - nm), w2 = __expf(e2 - nm), w3 = __expf(e3 - nm);
    float w4 = __expf(e4 - nm), w5 = __expf(e5 - nm), w6 = __expf(e6 - nm), w7 = __expf(e7 - nm);
    d = d * sc + ((w0 + w1) + (w2 + w3)) + ((w4 + w5) + (w6 + w7));
    acc = acc * sc +
          (w0 * __half2float(p0) + w1 * __half2float(p1) + w2 * __half2float(p2) +
           w3 * __half2float(p3)) +
          (w4 * __half2float(p4) + w5 * __half2float(p5) + w6 * __half2float(p6) +
           w7 * __half2float(p7));
    m = nm;
  }
  for (; i + 4 <= end; i += 4) {
    int s0 = csr_src[i], s1 = csr_src[i + 1], s2 = csr_src[i + 2], s3 = csr_src[i + 3];
    float e0 = lrelu(a_src[s0] + ad), e1 = lrelu(a_src[s1] + ad);
    float e2 = lrelu(a_src[s2] + ad), e3 = lrelu(a_src[s3] + ad);
    __half p0 = h[(size_t)s0 * 64 + l], p1 = h[(size_t)s1 * 64 + l];
    __half p2 = h[(size_t)s2 * 64 + l], p3 = h[(size_t)s3 * 64 + l];
    float nm = fmaxf(fmaxf(m, e0), fmaxf(fmaxf(e1, e2), e3));
    float sc = __expf(m - nm);
    float w0 = __expf(e0 - nm), w1 = __expf(e1 - nm), w2 = __expf(e2 - nm), w3 = __expf(e3 - nm);
    d = d * sc + (w0 + w1) + (w2 + w3);
    acc = acc * sc + w0 * __half2float(p0) + w1 * __half2float(p1) + w2 * __half2float(p2) +
          w3 * __half2float(p3);
    m = nm;
  }
  for (; i < end; i++) {
    int s = csr_src[i];
    float ee = lrelu(a_src[s] + ad);
    __half pp = h[(size_t)s * 64 + l];
    float nm = fmaxf(m, ee);
    float sc = __expf(m - nm);
    float w = __expf(ee - nm);
    d = d * sc + w;
    acc = acc * sc + w * __half2float(pp);
    m = nm;
  }
  out[(size_t)node * 64 + l] = acc / d + bias[l];
}

// ---------------- launch ----------------
extern "C" void kernel_launch(void* const* d_in, const int* in_sizes, int n_in,
                              void* d_out, int out_size, void* d_ws, size_t ws_size,
                              hipStream_t stream) {
  const float* data = (const float*)d_in[0];
  const int* ei = (const int*)d_in[1];
  const float* W0 = (const float*)d_in[2];
  const float* att_src0 = (const float*)d_in[3];
  const float* att_dst0 = (const float*)d_in[4];
  const float* bias0 = (const float*)d_in[5];
  const float* gamma0 = (const float*)d_in[6];
  const float* beta0 = (const float*)d_in[7];
  const float* W1 = (const float*)d_in[8];
  const float* att_src1 = (const float*)d_in[9];
  const float* att_dst1 = (const float*)d_in[10];
  const float* bias1 = (const float*)d_in[11];
  float* out = (float*)d_out;

  char* ws = (char*)d_ws;
  size_t off = 0;
  auto alloc = [&](size_t bytes) -> void* {
    void* p = ws + off;
    off = (off + bytes + 255) & ~(size_t)255;
    return p;
  };
  int* bucket_cnt = (int*)alloc(NBK * 4);
  int* bucket_base = (int*)alloc((NBK + 1) * 4);
  int* bin_cursor = (int*)alloc(NBK * 4);
  int* row_ptr = (int*)alloc((N_NODES + 1) * 4);
  unsigned int* binned = (unsigned int*)alloc((size_t)E_EDGES * 4);
  int* csr_src = (int*)alloc((size_t)E_EDGES * 4);
  __half* h0 = (__half*)alloc((size_t)N_NODES * 128 * 2);  // fp16 h
  float* a_s0 = (float*)alloc((size_t)N_NODES * 2 * 4);
  float* a_d0 = (float*)alloc((size_t)N_NODES * 2 * 4);
  float* out0 = (float*)alloc((size_t)N_NODES * 128 * 4);
  float* bn_sum = (float*)alloc(128 * 4);
  float* bn_sumsq = (float*)alloc(128 * 4);
  float* bn_scale = (float*)alloc(128 * 4);
  float* bn_shift = (float*)alloc(128 * 4);
  __half* h1 = h0;   // layer-1 buffers alias dead layer-0 buffers
  float* a_s1 = a_s0;
  float* a_d1 = a_d0;

  const int* srcArr = ei;
  const int* dstArr = ei + E_EDGES;

  k_zero<<<1, 256, 0, stream>>>(bucket_cnt, bn_sum, bn_sumsq);
  k_histB<<<256, 256, 0, stream>>>(dstArr, bucket_cnt);
  k_scanB<<<1, 64, 0, stream>>>(bucket_cnt, bucket_base, bin_cursor);
  k_bin<<<BIN_BLOCKS, 256, 0, stream>>>(srcArr, dstArr, bin_cursor, binned);
  k_scatter3<<<NBK, 256, 0, stream>>>(bucket_base, binned, row_ptr, csr_src);
  k_gemm0<<<(N_NODES + 63) / 64, 256, 0, stream>>>(data, W0, att_src0, att_dst0, h0, a_s0, a_d0);
  k_agg0<<<(N_NODES + 3) / 4, 256, 0, stream>>>(row_ptr, csr_src, h0, a_s0, a_d0, bias0, out0);
  k_bnstats<<<1024, 256, 0, stream>>>(out0, bn_sum, bn_sumsq);
  k_bnfinal<<<1, 128, 0, stream>>>(bn_sum, bn_sumsq, gamma0, beta0, bn_scale, bn_shift);
  k_gemm1<<<(N_NODES + 63) / 64, 256, 0, stream>>>(out0, W1, bn_scale, bn_shift, att_src1,
                                                   att_dst1, h1, a_s1, a_d1);
  k_agg1<<<(N_NODES + 3) / 4, 256, 0, stream>>>(row_ptr, csr_src, h1, a_s1, a_d1, bias1, out);
}

// Round 7
// 301.138 us; speedup vs baseline: 1.4061x; 1.2655x over previous
//
#include <hip/hip_runtime.h>
#include <hip/hip_fp16.h>
#include <math.h>

#define N_NODES 50000
#define E_EDGES 800000
#define NEG_SLOPE 0.2f
#define BN_EPS 1e-5f

#define BK_SHIFT 9                       // 512-node buckets
#define NBK 98                           // ceil(50000/512)
#define L1_BLOCKS 256
#define L1_CHUNK (E_EDGES / L1_BLOCKS)   // 3125 exactly
#define CNT_N (NBK * L1_BLOCKS)          // 25088
#define SCG_BLOCKS ((CNT_N + 1023) / 1024)  // 25
#define STAGE_MAX 9216                   // per-bucket staging (mean 8192, +11 sigma)

__device__ __forceinline__ float lrelu(float v) { return v > 0.f ? v : NEG_SLOPE * v; }

// ---------------- init (BN accumulators only) ----------------
__global__ void k_zero(float* __restrict__ bn_sum, float* __restrict__ bn_sumsq) {
  int t = threadIdx.x;
  if (t < 128) { bn_sum[t] = 0.f; bn_sumsq[t] = 0.f; }
}

// ---- L1: per-block bucket histogram (atomic-free at global level) ----
__global__ __launch_bounds__(256) void k_l1hist(const int* __restrict__ dst,
                                                int* __restrict__ cnt) {
  __shared__ int lcnt[NBK];
  int t = threadIdx.x;
  if (t < NBK) lcnt[t] = 0;
  __syncthreads();
  int beg = blockIdx.x * L1_CHUNK, end = beg + L1_CHUNK;
  for (int e = beg + t; e < end; e += 256)
    atomicAdd(&lcnt[((unsigned int)dst[e]) >> BK_SHIFT], 1);
  __syncthreads();
  for (int b = t; b < NBK; b += 256) cnt[b * L1_BLOCKS + blockIdx.x] = lcnt[b];
}

// ---- generic hierarchical exclusive scan over CNT_N elements ----
__global__ __launch_bounds__(256) void k_scan1g(const int* __restrict__ cnt,
                                                int* __restrict__ tmp,
                                                int* __restrict__ bsums) {
  __shared__ int ts[256];
  int t = threadIdx.x;
  int base = blockIdx.x * 1024 + t * 4;
  int c0 = (base + 0 < CNT_N) ? cnt[base + 0] : 0;
  int c1 = (base + 1 < CNT_N) ? cnt[base + 1] : 0;
  int c2 = (base + 2 < CNT_N) ? cnt[base + 2] : 0;
  int c3 = (base + 3 < CNT_N) ? cnt[base + 3] : 0;
  int s = c0 + c1 + c2 + c3;
  ts[t] = s;
  __syncthreads();
  for (int off = 1; off < 256; off <<= 1) {
    int v = (t >= off) ? ts[t - off] : 0;
    __syncthreads();
    ts[t] += v;
    __syncthreads();
  }
  int excl = ts[t] - s;
  if (t == 255) bsums[blockIdx.x] = ts[255];
  if (base + 0 < CNT_N) tmp[base + 0] = excl;
  if (base + 1 < CNT_N) tmp[base + 1] = excl + c0;
  if (base + 2 < CNT_N) tmp[base + 2] = excl + c0 + c1;
  if (base + 3 < CNT_N) tmp[base + 3] = excl + c0 + c1 + c2;
}

__global__ void k_scan2g(int* __restrict__ bsums) {
  int t = threadIdx.x;  // single wave
  int orig = (t < SCG_BLOCKS) ? bsums[t] : 0;
  int v = orig;
#pragma unroll
  for (int off = 1; off < 64; off <<= 1) {
    int u = __shfl_up(v, off);
    if (t >= off) v += u;
  }
  if (t < SCG_BLOCKS) bsums[t] = v - orig;  // exclusive
}

// ---- L1 scatter: deterministic bases per (bucket,block); ~128B contiguous runs ----
__global__ __launch_bounds__(256) void k_l1scatter(const int* __restrict__ src,
                                                   const int* __restrict__ dst,
                                                   const int* __restrict__ tmp,
                                                   const int* __restrict__ bsums,
                                                   unsigned int* __restrict__ binned) {
  __shared__ int cur[NBK];
  int t = threadIdx.x;
  for (int b = t; b < NBK; b += 256) {
    int idx = b * L1_BLOCKS + blockIdx.x;
    cur[b] = tmp[idx] + bsums[idx >> 10];
  }
  __syncthreads();
  int beg = blockIdx.x * L1_CHUNK, end = beg + L1_CHUNK;
  for (int e = beg + t; e < end; e += 256) {
    unsigned int d = (unsigned int)dst[e];
    int b = d >> BK_SHIFT;
    int p = atomicAdd(&cur[b], 1);
    binned[p] = ((unsigned int)src[e] << 16) | d;
  }
}

__global__ void k_bbase(const int* __restrict__ tmp, const int* __restrict__ bsums,
                        int* __restrict__ bucket_base) {
  int b = threadIdx.x;  // 128 threads
  if (b < NBK) {
    int idx = b * L1_BLOCKS;
    bucket_base[b] = tmp[idx] + bsums[idx >> 10];
  }
  if (b == NBK) bucket_base[NBK] = E_EDGES;
}

// ---- L2: per-bucket LDS counting sort; coalesced csr writes + row_ptr ----
__global__ __launch_bounds__(256) void k_scatter3(const int* __restrict__ bucket_base,
                                                  const unsigned int* __restrict__ binned,
                                                  int* __restrict__ row_ptr,
                                                  int* __restrict__ csr_src) {
  __shared__ int cnt[512];
  __shared__ int staging[STAGE_MAX];  // 36 KB
  __shared__ int ts[256];
  int t = threadIdx.x;
  int b = blockIdx.x;
  int lo = b << BK_SHIFT;
  int hi = lo + 512; if (hi > N_NODES) hi = N_NODES;
  int nloc = hi - lo;
  int base = bucket_base[b];
  int end = bucket_base[b + 1];
  cnt[t] = 0; cnt[t + 256] = 0;
  __syncthreads();
  for (int i = base + t; i < end; i += 256)
    atomicAdd(&cnt[(binned[i] & 0xFFFFu) - lo], 1);
  __syncthreads();
  int c0 = cnt[2 * t], c1 = cnt[2 * t + 1];
  int pair = c0 + c1;
  ts[t] = pair;
  __syncthreads();
  for (int off = 1; off < 256; off <<= 1) {
    int v = (t >= off) ? ts[t - off] : 0;
    __syncthreads();
    ts[t] += v;
    __syncthreads();
  }
  int exclp = ts[t] - pair;
  cnt[2 * t] = exclp;
  cnt[2 * t + 1] = exclp + c0;
  if (2 * t < nloc) row_ptr[lo + 2 * t] = base + exclp;
  if (2 * t + 1 < nloc) row_ptr[lo + 2 * t + 1] = base + exclp + c0;
  if (b == NBK - 1 && t == 0) row_ptr[N_NODES] = E_EDGES;
  __syncthreads();
  for (int i = base + t; i < end; i += 256) {
    unsigned int v = binned[i];
    int d = (int)(v & 0xFFFFu) - lo;
    int p = atomicAdd(&cnt[d], 1);
    int s = (int)(v >> 16);
    if (p < STAGE_MAX) staging[p] = s;
    else csr_src[base + p] = s;  // overflow fallback (correct, uncoalesced)
  }
  __syncthreads();
  int tot = end - base;
  int lim = tot < STAGE_MAX ? tot : STAGE_MAX;
  for (int k = t; k < lim; k += 256) csr_src[base + k] = staging[k];
}

// ---------------- layer 0 GEMM: h0 = x @ W0 (fp16 out), + fused attention dots ----------------
__global__ __launch_bounds__(256) void k_gemm0(
    const float* __restrict__ x, const float* __restrict__ W,
    const float* __restrict__ att_s, const float* __restrict__ att_d,
    __half* __restrict__ h, float* __restrict__ a_src, float* __restrict__ a_dst) {
  __shared__ float xs[64 * 132];
  int t = threadIdx.x;
  int rowBase = blockIdx.x * 64;
#pragma unroll
  for (int j = 0; j < 8; j++) {
    int id = t + 256 * j;
    int row = id >> 5;
    int kk = (id & 31) * 4;
    float4 v = make_float4(0.f, 0.f, 0.f, 0.f);
    int gr = rowBase + row;
    if (gr < N_NODES) v = *(const float4*)&x[(size_t)gr * 128 + kk];
    *(float4*)&xs[row * 132 + kk] = v;
  }
  __syncthreads();

  int tc = t & 31, tr = t >> 5;
  int c = tc * 4, r0 = tr * 8;
  float acc[8][4];
#pragma unroll
  for (int i = 0; i < 8; i++)
#pragma unroll
    for (int j = 0; j < 4; j++) acc[i][j] = 0.f;

  for (int k4 = 0; k4 < 128; k4 += 4) {
    float4 wv[4];
#pragma unroll
    for (int kk = 0; kk < 4; kk++) wv[kk] = *(const float4*)&W[(k4 + kk) * 128 + c];
    float4 xv[8];
#pragma unroll
    for (int i = 0; i < 8; i++) xv[i] = *(const float4*)&xs[(r0 + i) * 132 + k4];
#pragma unroll
    for (int i = 0; i < 8; i++) {
      acc[i][0] += xv[i].x * wv[0].x + xv[i].y * wv[1].x + xv[i].z * wv[2].x + xv[i].w * wv[3].x;
      acc[i][1] += xv[i].x * wv[0].y + xv[i].y * wv[1].y + xv[i].z * wv[2].y + xv[i].w * wv[3].y;
      acc[i][2] += xv[i].x * wv[0].z + xv[i].y * wv[1].z + xv[i].z * wv[2].z + xv[i].w * wv[3].z;
      acc[i][3] += xv[i].x * wv[0].w + xv[i].y * wv[1].w + xv[i].z * wv[2].w + xv[i].w * wv[3].w;
    }
  }

  float as4[4], ad4[4];
#pragma unroll
  for (int j = 0; j < 4; j++) { as4[j] = att_s[c + j]; ad4[j] = att_d[c + j]; }
  int head = tc >> 4;
#pragma unroll
  for (int i = 0; i < 8; i++) {
    int gr = rowBase + r0 + i;
    float ps = acc[i][0] * as4[0] + acc[i][1] * as4[1] + acc[i][2] * as4[2] + acc[i][3] * as4[3];
    float pd = acc[i][0] * ad4[0] + acc[i][1] * ad4[1] + acc[i][2] * ad4[2] + acc[i][3] * ad4[3];
#pragma unroll
    for (int msk = 1; msk <= 8; msk <<= 1) {
      ps += __shfl_xor(ps, msk);
      pd += __shfl_xor(pd, msk);
    }
    if (gr < N_NODES) {
      __half2 p01 = __floats2half2_rn(acc[i][0], acc[i][1]);
      __half2 p23 = __floats2half2_rn(acc[i][2], acc[i][3]);
      uint2 pk;
      pk.x = *(unsigned int*)&p01;
      pk.y = *(unsigned int*)&p23;
      *(uint2*)&h[(size_t)gr * 128 + c] = pk;
      if ((t & 15) == 0) {
        a_src[gr * 2 + head] = ps;
        a_dst[gr * 2 + head] = pd;
      }
    }
  }
}

// ---------------- layer 0 aggregation: wave per node, batched-8 online softmax, fp16 h --------
__global__ __launch_bounds__(256) void k_agg0(
    const int* __restrict__ row_ptr, const int* __restrict__ csr_src,
    const __half* __restrict__ h, const float* __restrict__ a_src,
    const float* __restrict__ a_dst, const float* __restrict__ bias,
    float* __restrict__ out) {
  int node = (blockIdx.x * blockDim.x + threadIdx.x) >> 6;
  if (node >= N_NODES) return;
  int l = threadIdx.x & 63;
  int head = l >> 5;
  int c = l * 2;
  float ad = a_dst[node * 2 + head];
  float m = lrelu(a_src[node * 2 + head] + ad);  // self-loop
  float d = 1.f;
  float2 hv = __half22float2(*(const __half2*)&h[(size_t)node * 128 + c]);
  float acc0 = hv.x, acc1 = hv.y;
  int beg = row_ptr[node], end = row_ptr[node + 1];
  int i = beg;
  for (; i + 8 <= end; i += 8) {
    int s0 = csr_src[i], s1 = csr_src[i + 1], s2 = csr_src[i + 2], s3 = csr_src[i + 3];
    int s4 = csr_src[i + 4], s5 = csr_src[i + 5], s6 = csr_src[i + 6], s7 = csr_src[i + 7];
    float e0 = lrelu(a_src[s0 * 2 + head] + ad), e1 = lrelu(a_src[s1 * 2 + head] + ad);
    float e2 = lrelu(a_src[s2 * 2 + head] + ad), e3 = lrelu(a_src[s3 * 2 + head] + ad);
    float e4 = lrelu(a_src[s4 * 2 + head] + ad), e5 = lrelu(a_src[s5 * 2 + head] + ad);
    float e6 = lrelu(a_src[s6 * 2 + head] + ad), e7 = lrelu(a_src[s7 * 2 + head] + ad);
    __half2 p0 = *(const __half2*)&h[(size_t)s0 * 128 + c];
    __half2 p1 = *(const __half2*)&h[(size_t)s1 * 128 + c];
    __half2 p2 = *(const __half2*)&h[(size_t)s2 * 128 + c];
    __half2 p3 = *(const __half2*)&h[(size_t)s3 * 128 + c];
    __half2 p4 = *(const __half2*)&h[(size_t)s4 * 128 + c];
    __half2 p5 = *(const __half2*)&h[(size_t)s5 * 128 + c];
    __half2 p6 = *(const __half2*)&h[(size_t)s6 * 128 + c];
    __half2 p7 = *(const __half2*)&h[(size_t)s7 * 128 + c];
    float nm = fmaxf(m, fmaxf(fmaxf(fmaxf(e0, e1), fmaxf(e2, e3)),
                              fmaxf(fmaxf(e4, e5), fmaxf(e6, e7))));
    float sc = __expf(m - nm);
    float w0 = __expf(e0 - nm), w1 = __expf(e1 - nm), w2 = __expf(e2 - nm), w3 = __expf(e3 - nm);
    float w4 = __expf(e4 - nm), w5 = __expf(e5 - nm), w6 = __expf(e6 - nm), w7 = __expf(e7 - nm);
    d = d * sc + ((w0 + w1) + (w2 + w3)) + ((w4 + w5) + (w6 + w7));
    float2 f0 = __half22float2(p0), f1 = __half22float2(p1);
    float2 f2 = __half22float2(p2), f3 = __half22float2(p3);
    float2 f4 = __half22float2(p4), f5 = __half22float2(p5);
    float2 f6 = __half22float2(p6), f7 = __half22float2(p7);
    acc0 = acc0 * sc + (w0 * f0.x + w1 * f1.x + w2 * f2.x + w3 * f3.x) +
           (w4 * f4.x + w5 * f5.x + w6 * f6.x + w7 * f7.x);
    acc1 = acc1 * sc + (w0 * f0.y + w1 * f1.y + w2 * f2.y + w3 * f3.y) +
           (w4 * f4.y + w5 * f5.y + w6 * f6.y + w7 * f7.y);
    m = nm;
  }
  for (; i + 4 <= end; i += 4) {
    int s0 = csr_src[i], s1 = csr_src[i + 1], s2 = csr_src[i + 2], s3 = csr_src[i + 3];
    float e0 = lrelu(a_src[s0 * 2 + head] + ad), e1 = lrelu(a_src[s1 * 2 + head] + ad);
    float e2 = lrelu(a_src[s2 * 2 + head] + ad), e3 = lrelu(a_src[s3 * 2 + head] + ad);
    __half2 p0 = *(const __half2*)&h[(size_t)s0 * 128 + c];
    __half2 p1 = *(const __half2*)&h[(size_t)s1 * 128 + c];
    __half2 p2 = *(const __half2*)&h[(size_t)s2 * 128 + c];
    __half2 p3 = *(const __half2*)&h[(size_t)s3 * 128 + c];
    float nm = fmaxf(fmaxf(m, e0), fmaxf(fmaxf(e1, e2), e3));
    float sc = __expf(m - nm);
    float w0 = __expf(e0 - nm), w1 = __expf(e1 - nm), w2 = __expf(e2 - nm), w3 = __expf(e3 - nm);
    d = d * sc + (w0 + w1) + (w2 + w3);
    float2 f0 = __half22float2(p0), f1 = __half22float2(p1);
    float2 f2 = __half22float2(p2), f3 = __half22float2(p3);
    acc0 = acc0 * sc + w0 * f0.x + w1 * f1.x + w2 * f2.x + w3 * f3.x;
    acc1 = acc1 * sc + w0 * f0.y + w1 * f1.y + w2 * f2.y + w3 * f3.y;
    m = nm;
  }
  for (; i < end; i++) {
    int s = csr_src[i];
    float ee = lrelu(a_src[s * 2 + head] + ad);
    __half2 pp = *(const __half2*)&h[(size_t)s * 128 + c];
    float nm = fmaxf(m, ee);
    float sc = __expf(m - nm);
    float w = __expf(ee - nm);
    float2 ff = __half22float2(pp);
    d = d * sc + w;
    acc0 = acc0 * sc + w * ff.x;
    acc1 = acc1 * sc + w * ff.y;
    m = nm;
  }
  float inv = 1.f / d;
  float2 o;
  o.x = acc0 * inv + bias[c];
  o.y = acc1 * inv + bias[c + 1];
  *(float2*)&out[(size_t)node * 128 + c] = o;
}

// ---------------- BatchNorm stats ----------------
__global__ __launch_bounds__(256) void k_bnstats(const float* __restrict__ x,
                                                 float* __restrict__ bn_sum,
                                                 float* __restrict__ bn_sumsq) {
  int f = threadIdx.x & 127;
  int half = threadIdx.x >> 7;
  float s = 0.f, s2 = 0.f;
  for (int r = blockIdx.x * 2 + half; r < N_NODES; r += gridDim.x * 2) {
    float v = x[(size_t)r * 128 + f];
    s += v;
    s2 += v * v;
  }
  __shared__ float ls[256], ls2[256];
  ls[threadIdx.x] = s;
  ls2[threadIdx.x] = s2;
  __syncthreads();
  if (half == 0) {
    atomicAdd(&bn_sum[f], s + ls[f + 128]);
    atomicAdd(&bn_sumsq[f], s2 + ls2[f + 128]);
  }
}

__global__ void k_bnfinal(const float* __restrict__ sum, const float* __restrict__ sumsq,
                          const float* __restrict__ gamma, const float* __restrict__ beta,
                          float* __restrict__ scale, float* __restrict__ shift) {
  int f = threadIdx.x;
  float mu = sum[f] / (float)N_NODES;
  float var = sumsq[f] / (float)N_NODES - mu * mu;
  float sc = gamma[f] * rsqrtf(var + BN_EPS);
  scale[f] = sc;
  shift[f] = beta[f] - mu * sc;
}

// ---------------- layer 1 GEMM (BN+ELU fused on load), fp16 h out ----------------
__global__ __launch_bounds__(256) void k_gemm1(
    const float* __restrict__ x, const float* __restrict__ W,
    const float* __restrict__ scale, const float* __restrict__ shift,
    const float* __restrict__ att_s, const float* __restrict__ att_d,
    __half* __restrict__ h, float* __restrict__ a_src, float* __restrict__ a_dst) {
  __shared__ float xs[64 * 132];
  int t = threadIdx.x;
  int rowBase = blockIdx.x * 64;
#pragma unroll
  for (int j = 0; j < 8; j++) {
    int id = t + 256 * j;
    int row = id >> 5;
    int kk = (id & 31) * 4;
    float4 v = make_float4(0.f, 0.f, 0.f, 0.f);
    int gr = rowBase + row;
    if (gr < N_NODES) {
      float4 raw = *(const float4*)&x[(size_t)gr * 128 + kk];
      float4 sc = *(const float4*)&scale[kk];
      float4 sh = *(const float4*)&shift[kk];
      v.x = raw.x * sc.x + sh.x;
      v.y = raw.y * sc.y + sh.y;
      v.z = raw.z * sc.z + sh.z;
      v.w = raw.w * sc.w + sh.w;
      v.x = v.x > 0.f ? v.x : __expf(v.x) - 1.f;
      v.y = v.y > 0.f ? v.y : __expf(v.y) - 1.f;
      v.z = v.z > 0.f ? v.z : __expf(v.z) - 1.f;
      v.w = v.w > 0.f ? v.w : __expf(v.w) - 1.f;
    }
    *(float4*)&xs[row * 132 + kk] = v;
  }
  __syncthreads();

  int tc = t & 15, tr = t >> 4;
  int c = tc * 4, r0 = tr * 4;
  float acc[4][4];
#pragma unroll
  for (int i = 0; i < 4; i++)
#pragma unroll
    for (int j = 0; j < 4; j++) acc[i][j] = 0.f;

  for (int k4 = 0; k4 < 128; k4 += 4) {
    float4 wv[4];
#pragma unroll
    for (int kk = 0; kk < 4; kk++) wv[kk] = *(const float4*)&W[(k4 + kk) * 64 + c];
    float4 xv[4];
#pragma unroll
    for (int i = 0; i < 4; i++) xv[i] = *(const float4*)&xs[(r0 + i) * 132 + k4];
#pragma unroll
    for (int i = 0; i < 4; i++) {
      acc[i][0] += xv[i].x * wv[0].x + xv[i].y * wv[1].x + xv[i].z * wv[2].x + xv[i].w * wv[3].x;
      acc[i][1] += xv[i].x * wv[0].y + xv[i].y * wv[1].y + xv[i].z * wv[2].y + xv[i].w * wv[3].y;
      acc[i][2] += xv[i].x * wv[0].z + xv[i].y * wv[1].z + xv[i].z * wv[2].z + xv[i].w * wv[3].z;
      acc[i][3] += xv[i].x * wv[0].w + xv[i].y * wv[1].w + xv[i].z * wv[2].w + xv[i].w * wv[3].w;
    }
  }

  float as4[4], ad4[4];
#pragma unroll
  for (int j = 0; j < 4; j++) { as4[j] = att_s[c + j]; ad4[j] = att_d[c + j]; }
#pragma unroll
  for (int i = 0; i < 4; i++) {
    int gr = rowBase + r0 + i;
    float ps = acc[i][0] * as4[0] + acc[i][1] * as4[1] + acc[i][2] * as4[2] + acc[i][3] * as4[3];
    float pd = acc[i][0] * ad4[0] + acc[i][1] * ad4[1] + acc[i][2] * ad4[2] + acc[i][3] * ad4[3];
#pragma unroll
    for (int msk = 1; msk <= 8; msk <<= 1) {
      ps += __shfl_xor(ps, msk);
      pd += __shfl_xor(pd, msk);
    }
    if (gr < N_NODES) {
      __half2 p01 = __floats2half2_rn(acc[i][0], acc[i][1]);
      __half2 p23 = __floats2half2_rn(acc[i][2], acc[i][3]);
      uint2 pk;
      pk.x = *(unsigned int*)&p01;
      pk.y = *(unsigned int*)&p23;
      *(uint2*)&h[(size_t)gr * 64 + c] = pk;
      if ((t & 15) == 0) {
        a_src[gr] = ps;
        a_dst[gr] = pd;
      }
    }
  }
}

// ---------------- layer 1 aggregation: batched-8, fp16 h ----------------
__global__ __launch_bounds__(256) void k_agg1(
    const int* __restrict__ row_ptr, const int* __restrict__ csr_src,
    const __half* __restrict__ h, const float* __restrict__ a_src,
    const float* __restrict__ a_dst, const float* __restrict__ bias,
    float* __restrict__ out) {
  int node = (blockIdx.x * blockDim.x + threadIdx.x) >> 6;
  if (node >= N_NODES) return;
  int l = threadIdx.x & 63;
  float ad = a_dst[node];
  float m = lrelu(a_src[node] + ad);  // self loop
  float d = 1.f;
  float acc = __half2float(h[(size_t)node * 64 + l]);
  int beg = row_ptr[node], end = row_ptr[node + 1];
  int i = beg;
  for (; i + 8 <= end; i += 8) {
    int s0 = csr_src[i], s1 = csr_src[i + 1], s2 = csr_src[i + 2], s3 = csr_src[i + 3];
    int s4 = csr_src[i + 4], s5 = csr_src[i + 5], s6 = csr_src[i + 6], s7 = csr_src[i + 7];
    float e0 = lrelu(a_src[s0] + ad), e1 = lrelu(a_src[s1] + ad);
    float e2 = lrelu(a_src[s2] + ad), e3 = lrelu(a_src[s3] + ad);
    float e4 = lrelu(a_src[s4] + ad), e5 = lrelu(a_src[s5] + ad);
    float e6 = lrelu(a_src[s6] + ad), e7 = lrelu(a_src[s7] + ad);
    __half p0 = h[(size_t)s0 * 64 + l], p1 = h[(size_t)s1 * 64 + l];
    __half p2 = h[(size_t)s2 * 64 + l], p3 = h[(size_t)s3 * 64 + l];
    __half p4 = h[(size_t)s4 * 64 + l], p5 = h[(size_t)s5 * 64 + l];
    __half p6 = h[(size_t)s6 * 64 + l], p7 = h[(size_t)s7 * 64 + l];
    float nm = fmaxf(m, fmaxf(fmaxf(fmaxf(e0, e1), fmaxf(e2, e3)),
                              fmaxf(fmaxf(e4, e5), fmaxf(e6, e7))));
    float sc = __expf(m - nm);
    float w0 = __expf(e0 - nm), w1 = __expf(e1 - nm), w2 = __expf(e2 - nm), w3 = __expf(e3 - nm);
    float w4 = __expf(e4 - nm), w5 = __expf(e5 - nm), w6 = __expf(e6 - nm), w7 = __expf(e7 - nm);
    d = d * sc + ((w0 + w1) + (w2 + w3)) + ((w4 + w5) + (w6 + w7));
    acc = acc * sc +
          (w0 * __half2float(p0) + w1 * __half2float(p1) + w2 * __half2float(p2) +
           w3 * __half2float(p3)) +
          (w4 * __half2float(p4) + w5 * __half2float(p5) + w6 * __half2float(p6) +
           w7 * __half2float(p7));
    m = nm;
  }
  for (; i + 4 <= end; i += 4) {
    int s0 = csr_src[i], s1 = csr_src[i + 1], s2 = csr_src[i + 2], s3 = csr_src[i + 3];
    float e0 = lrelu(a_src[s0] + ad), e1 = lrelu(a_src[s1] + ad);
    float e2 = lrelu(a_src[s2] + ad), e3 = lrelu(a_src[s3] + ad);
    __half p0 = h[(size_t)s0 * 64 + l], p1 = h[(size_t)s1 * 64 + l];
    __half p2 = h[(size_t)s2 * 64 + l], p3 = h[(size_t)s3 * 64 + l];
    float nm = fmaxf(fmaxf(m, e0), fmaxf(fmaxf(e1, e2), e3));
    float sc = __expf(m - nm);
    float w0 = __expf(e0 - nm), w1 = __expf(e1 - nm), w2 = __expf(e2 - nm), w3 = __expf(e3 - nm);
    d = d * sc + (w0 + w1) + (w2 + w3);
    acc = acc * sc + w0 * __half2float(p0) + w1 * __half2float(p1) + w2 * __half2float(p2) +
          w3 * __half2float(p3);
    m = nm;
  }
  for (; i < end; i++) {
    int s = csr_src[i];
    float ee = lrelu(a_src[s] + ad);
    __half pp = h[(size_t)s * 64 + l];
    float nm = fmaxf(m, ee);
    float sc = __expf(m - nm);
    float w = __expf(ee - nm);
    d = d * sc + w;
    acc = acc * sc + w * __half2float(pp);
    m = nm;
  }
  out[(size_t)node * 64 + l] = acc / d + bias[l];
}

// ---------------- launch ----------------
extern "C" void kernel_launch(void* const* d_in, const int* in_sizes, int n_in,
                              void* d_out, int out_size, void* d_ws, size_t ws_size,
                              hipStream_t stream) {
  const float* data = (const float*)d_in[0];
  const int* ei = (const int*)d_in[1];
  const float* W0 = (const float*)d_in[2];
  const float* att_src0 = (const float*)d_in[3];
  const float* att_dst0 = (const float*)d_in[4];
  const float* bias0 = (const float*)d_in[5];
  const float* gamma0 = (const float*)d_in[6];
  const float* beta0 = (const float*)d_in[7];
  const float* W1 = (const float*)d_in[8];
  const float* att_src1 = (const float*)d_in[9];
  const float* att_dst1 = (const float*)d_in[10];
  const float* bias1 = (const float*)d_in[11];
  float* out = (float*)d_out;

  char* ws = (char*)d_ws;
  size_t off = 0;
  auto alloc = [&](size_t bytes) -> void* {
    void* p = ws + off;
    off = (off + bytes + 255) & ~(size_t)255;
    return p;
  };
  int* cnt = (int*)alloc((size_t)CNT_N * 4);
  int* tmp = (int*)alloc((size_t)CNT_N * 4);
  int* bsums = (int*)alloc(32 * 4);
  int* bucket_base = (int*)alloc((NBK + 1) * 4);
  int* row_ptr = (int*)alloc((N_NODES + 1) * 4);
  unsigned int* binned = (unsigned int*)alloc((size_t)E_EDGES * 4);
  int* csr_src = (int*)alloc((size_t)E_EDGES * 4);
  __half* h0 = (__half*)alloc((size_t)N_NODES * 128 * 2);  // fp16 h
  float* a_s0 = (float*)alloc((size_t)N_NODES * 2 * 4);
  float* a_d0 = (float*)alloc((size_t)N_NODES * 2 * 4);
  float* out0 = (float*)alloc((size_t)N_NODES * 128 * 4);
  float* bn_sum = (float*)alloc(128 * 4);
  float* bn_sumsq = (float*)alloc(128 * 4);
  float* bn_scale = (float*)alloc(128 * 4);
  float* bn_shift = (float*)alloc(128 * 4);
  __half* h1 = h0;   // layer-1 buffers alias dead layer-0 buffers
  float* a_s1 = a_s0;
  float* a_d1 = a_d0;

  const int* srcArr = ei;
  const int* dstArr = ei + E_EDGES;

  k_zero<<<1, 128, 0, stream>>>(bn_sum, bn_sumsq);
  k_l1hist<<<L1_BLOCKS, 256, 0, stream>>>(dstArr, cnt);
  k_scan1g<<<SCG_BLOCKS, 256, 0, stream>>>(cnt, tmp, bsums);
  k_scan2g<<<1, 64, 0, stream>>>(bsums);
  k_l1scatter<<<L1_BLOCKS, 256, 0, stream>>>(srcArr, dstArr, tmp, bsums, binned);
  k_bbase<<<1, 128, 0, stream>>>(tmp, bsums, bucket_base);
  k_scatter3<<<NBK, 256, 0, stream>>>(bucket_base, binned, row_ptr, csr_src);
  k_gemm0<<<(N_NODES + 63) / 64, 256, 0, stream>>>(data, W0, att_src0, att_dst0, h0, a_s0, a_d0);
  k_agg0<<<(N_NODES + 3) / 4, 256, 0, stream>>>(row_ptr, csr_src, h0, a_s0, a_d0, bias0, out0);
  k_bnstats<<<1024, 256, 0, stream>>>(out0, bn_sum, bn_sumsq);
  k_bnfinal<<<1, 128, 0, stream>>>(bn_sum, bn_sumsq, gamma0, beta0, bn_scale, bn_shift);
  k_gemm1<<<(N_NODES + 63) / 64, 256, 0, stream>>>(out0, W1, bn_scale, bn_shift, att_src1,
                                                   att_dst1, h1, a_s1, a_d1);
  k_agg1<<<(N_NODES + 3) / 4, 256, 0, stream>>>(row_ptr, csr_src, h1, a_s1, a_d1, bias1, out);
}